// Round 7
// baseline (190.535 us; speedup 1.0000x reference)
//
#include <hip/hip_runtime.h>

// Problem: B=64, S=128, D_MODEL=D_INNER=1024  ->  M = B*S = 8192, K = N = 1024.
// Reference simplifies: numerator/denominator == v exactly (dw>0, exp_k>0 cancel),
// so out = (sigmoid(emb@Wq+bq) * (emb@Wv+bv)) @ Wo + bo.  Wk, bk, w are dead inputs.
//
// R13: qv ported into bt's EXACT proven structure (the only one measured at
// ~905 TF this session): 128x128 tile, 256 thr (4 waves 2x2, wave 64x64),
// single-buffered simple __syncthreads loop, BK=64, 16 iters, grid (64,8)=512
// -> 2 independent blocks/CU (the cross-block TLP bt proves). Third LDS panel
// for Bv (48 KiB). Dual accumulators (q and v) reuse the same A fragments:
// 64 MFMA / 24 ds_reads / 12 GLDS per wave-iter (better MFMA density than bt's
// 32/16/8). R12's failure: "2 blocks/CU" of 256thr = same 8 waves/CU as one
// 512thr block -> no new TLP + 2x iterations. This keeps 16 iters and real
// block independence. Schedule variants are dead (R7-R11 all ~41us); this is
// the structure lever.
// bt, prep frozen (R9-proven). Harness fills 256MiB ~41us x2/rep are fixed.

typedef short bf16x8 __attribute__((ext_vector_type(8)));  // 8 bf16 = 4 VGPRs
typedef float f32x4  __attribute__((ext_vector_type(4)));

__device__ __forceinline__ short f2bf(float f) {  // RNE fp32 -> bf16
  union { float f; unsigned u; } x; x.f = f;
  unsigned r = x.u + 0x7fffu + ((x.u >> 16) & 1u);
  return (short)(r >> 16);
}

struct alignas(16) S8 { short v[8]; };

#define GLDS(g, l) \
  __builtin_amdgcn_global_load_lds((const __attribute__((address_space(1))) void*)(g), \
                                   (__attribute__((address_space(3))) void*)(l), 16, 0, 0)
#define MFMA(a, b, c) __builtin_amdgcn_mfma_f32_16x16x32_bf16((a), (b), (c), 0, 0, 0)

// ---- Phase 0: emb fp32->bf16 + transpose/cast the three 1024x1024 weights ----
__global__ __launch_bounds__(256) void prep_kernel(
    const float* __restrict__ emb, const float* __restrict__ Wq, const float* __restrict__ Wv,
    const float* __restrict__ Wo, short* __restrict__ embB, short* __restrict__ WqvT,
    short* __restrict__ WoT) {
  __shared__ float tr[64 * 65];  // pad 65 breaks column-read conflicts
  const int t = threadIdx.x;
  const int bid = blockIdx.x;
  const int gdim = gridDim.x;

  // emb cast: 1048576 groups of 8 floats -> 8 bf16
  for (size_t i = (size_t)bid * 256 + t; i < 1048576; i += (size_t)gdim * 256) {
    const float4* p = (const float4*)emb + i * 2;
    float4 a = p[0], b = p[1];
    S8 s;
    s.v[0] = f2bf(a.x); s.v[1] = f2bf(a.y); s.v[2] = f2bf(a.z); s.v[3] = f2bf(a.w);
    s.v[4] = f2bf(b.x); s.v[5] = f2bf(b.y); s.v[6] = f2bf(b.z); s.v[7] = f2bf(b.w);
    ((S8*)embB)[i] = s;
  }

  // weight transposes: 3 * 256 = 768 tiles of 64x64 (one per block at grid 768)
  const int rr = t >> 4, cc4 = (t & 15) * 4;     // read coords
  const int orow = t >> 3, ocol8 = (t & 7) * 8;  // write coords
  for (int z = bid; z < 768; z += gdim) {
    const float* in; short* op; int ti;
    if (z < 256)      { in = Wq; op = WqvT;           ti = z; }
    else if (z < 512) { in = Wv; op = WqvT + 1048576; ti = z - 256; }
    else              { in = Wo; op = WoT;            ti = z - 512; }
    const int bx = (ti & 15) * 64, by = (ti >> 4) * 64;
    __syncthreads();  // protect LDS reuse across z-iterations
#pragma unroll
    for (int k = 0; k < 4; ++k) {
      float4 v = *(const float4*)&in[(size_t)(by + rr + 16 * k) * 1024 + bx + cc4];
      float* d = &tr[(rr + 16 * k) * 65 + cc4];
      d[0] = v.x; d[1] = v.y; d[2] = v.z; d[3] = v.w;
    }
    __syncthreads();
#pragma unroll
    for (int h = 0; h < 2; ++h) {
      const int oc = orow + 32 * h;  // output row within tile = input col
      S8 s;
#pragma unroll
      for (int i = 0; i < 8; ++i) s.v[i] = f2bf(tr[(ocol8 + i) * 65 + oc]);
      *(S8*)&op[(size_t)(bx + oc) * 1024 + by + ocol8] = s;  // 16B, 128B runs
    }
  }
}

// ---- Phase 1: X = sigmoid(embB@WqT+bq) * (embB@WvT+bv), bf16. ----
// R13: bt's exact structure + third panel. 128x128 tile, 256 thr (4 waves 2x2,
// wave 64x64 of q AND v), BK=64, single-buffer 48 KiB, simple syncthreads loop,
// grid (64,8) = 512 blocks = 2 independent blocks/CU.
__global__ __launch_bounds__(256) void gemm_qv_kernel(
    const short* __restrict__ A, const short* __restrict__ BT,  // BT=[WqT|WvT] 2048x1024
    const float* __restrict__ bq, const float* __restrict__ bv, short* __restrict__ X) {
  __shared__ short As[128 * 64];   // 16 KiB
  __shared__ short Bqs[128 * 64];  // 16 KiB
  __shared__ short Bvs[128 * 64];  // 16 KiB
  const int t = threadIdx.x;
  const int lane = t & 63;
  const int w = t >> 6;
  const int l16 = lane & 15;
  const int quad = lane >> 4;
  const int bm = blockIdx.x * 128;
  const int bn = blockIdx.y * 128;
  const int wm = (w & 1) * 64;
  const int wn = (w >> 1) * 64;

  const int r8 = t >> 3;                     // 0..31: row within a 32-row sweep
  const int swe = ((t & 7) ^ (r8 & 7)) * 8;  // pre-swizzled source chunk
  const short* pA0 = A + (size_t)(bm + r8) * 1024 + swe;
  const short* pA1 = pA0 + 32 * 1024;
  const short* pA2 = pA0 + 64 * 1024;
  const short* pA3 = pA0 + 96 * 1024;
  const short* pQ0 = BT + (size_t)(bn + r8) * 1024 + swe;
  const short* pQ1 = pQ0 + 32 * 1024;
  const short* pQ2 = pQ0 + 64 * 1024;
  const short* pQ3 = pQ0 + 96 * 1024;
  const short* pV0 = BT + (size_t)(1024 + bn + r8) * 1024 + swe;
  const short* pV1 = pV0 + 32 * 1024;
  const short* pV2 = pV0 + 64 * 1024;
  const short* pV3 = pV0 + 96 * 1024;
  short* lA = As + w * 512;   // wave-uniform base; HW adds lane*16B
  short* lQ = Bqs + w * 512;
  short* lV = Bvs + w * 512;

  const int qsw0 = (quad ^ (l16 & 7)) * 8;        // k-half 0 chunk swizzle
  const int qsw1 = ((quad + 4) ^ (l16 & 7)) * 8;  // k-half 1
  const short* fA0 = As + (wm + l16) * 64 + qsw0;
  const short* fA1 = As + (wm + l16) * 64 + qsw1;
  const short* fQ0 = Bqs + (wn + l16) * 64 + qsw0;
  const short* fQ1 = Bqs + (wn + l16) * 64 + qsw1;
  const short* fV0 = Bvs + (wn + l16) * 64 + qsw0;
  const short* fV1 = Bvs + (wn + l16) * 64 + qsw1;

  f32x4 aq[4][4] = {};
  f32x4 av[4][4] = {};

  for (int it = 0; it < 16; ++it) {
    GLDS(pA0, lA); GLDS(pA1, lA + 2048); GLDS(pA2, lA + 4096); GLDS(pA3, lA + 6144);
    GLDS(pQ0, lQ); GLDS(pQ1, lQ + 2048); GLDS(pQ2, lQ + 4096); GLDS(pQ3, lQ + 6144);
    GLDS(pV0, lV); GLDS(pV1, lV + 2048); GLDS(pV2, lV + 4096); GLDS(pV3, lV + 6144);
    pA0 += 64; pA1 += 64; pA2 += 64; pA3 += 64;
    pQ0 += 64; pQ1 += 64; pQ2 += 64; pQ3 += 64;
    pV0 += 64; pV1 += 64; pV2 += 64; pV3 += 64;
    __syncthreads();

#pragma unroll
    for (int h = 0; h < 2; h++) {
      const short* fA = h ? fA1 : fA0;
      const short* fQ = h ? fQ1 : fQ0;
      const short* fV = h ? fV1 : fV0;
      bf16x8 a[4], bqf[4], bvf[4];
#pragma unroll
      for (int i = 0; i < 4; i++) {
        a[i] = *(const bf16x8*)(fA + i * 1024);
        bqf[i] = *(const bf16x8*)(fQ + i * 1024);
        bvf[i] = *(const bf16x8*)(fV + i * 1024);
      }
#pragma unroll
      for (int i = 0; i < 4; i++)
#pragma unroll
        for (int n = 0; n < 4; n++) {
          aq[i][n] = MFMA(a[i], bqf[n], aq[i][n]);
          av[i][n] = MFMA(a[i], bvf[n], av[i][n]);
        }
    }
    __syncthreads();
  }

  // epilogue: C/D layout col=lane&15, row=(lane>>4)*4+reg  [m89/m91-verified]
#pragma unroll
  for (int n = 0; n < 4; ++n) {
    const int col = bn + wn + n * 16 + l16;
    const float bql = bq[col], bvl = bv[col];
#pragma unroll
    for (int i = 0; i < 4; ++i)
#pragma unroll
      for (int r = 0; r < 4; ++r) {
        const int row = bm + wm + i * 16 + quad * 4 + r;
        const float q = aq[i][n][r] + bql;
        const float v = av[i][n][r] + bvl;
        const float sg = 1.0f / (1.0f + __expf(-q));
        X[(size_t)row * 1024 + col] = f2bf(sg * v);
      }
  }
}

// ---- Phase 2: out = X @ WoT^T + bo, fp32. R9-proven structure: 128x128 tile,
// BK=64, 256 thr (4 waves 2x2, wave 64x64), 32 KiB LDS, grid (64,8) = 512
// blocks = 2 blocks/CU. Inter-block TLP hides the staging drain. ----
__global__ __launch_bounds__(256) void gemm_bt_kernel(
    const short* __restrict__ A, const short* __restrict__ BT, float* __restrict__ C,
    const float* __restrict__ bias) {
  __shared__ short As[128 * 64];  // 16 KiB
  __shared__ short Bs[128 * 64];  // 16 KiB
  const int t = threadIdx.x;
  const int lane = t & 63;
  const int w = t >> 6;
  const int l16 = lane & 15;
  const int quad = lane >> 4;
  const int bm = blockIdx.x * 128;
  const int bn = blockIdx.y * 128;
  const int wm = (w & 1) * 64;
  const int wn = (w >> 1) * 64;

  const int r8 = t >> 3;
  const int swe = ((t & 7) ^ (r8 & 7)) * 8;
  const short* pA0 = A + (size_t)(bm + r8) * 1024 + swe;
  const short* pA1 = pA0 + 32 * 1024;
  const short* pA2 = pA0 + 64 * 1024;
  const short* pA3 = pA0 + 96 * 1024;
  const short* pB0 = BT + (size_t)(bn + r8) * 1024 + swe;
  const short* pB1 = pB0 + 32 * 1024;
  const short* pB2 = pB0 + 64 * 1024;
  const short* pB3 = pB0 + 96 * 1024;
  short* lA = As + w * 512;
  short* lB = Bs + w * 512;

  const int qsw0 = (quad ^ (l16 & 7)) * 8;
  const int qsw1 = ((quad + 4) ^ (l16 & 7)) * 8;
  const short* fA0 = As + (wm + l16) * 64 + qsw0;
  const short* fA1 = As + (wm + l16) * 64 + qsw1;
  const short* fB0 = Bs + (wn + l16) * 64 + qsw0;
  const short* fB1 = Bs + (wn + l16) * 64 + qsw1;

  f32x4 acc[4][4] = {};

  for (int it = 0; it < 16; ++it) {
    GLDS(pA0, lA); GLDS(pA1, lA + 2048); GLDS(pA2, lA + 4096); GLDS(pA3, lA + 6144);
    GLDS(pB0, lB); GLDS(pB1, lB + 2048); GLDS(pB2, lB + 4096); GLDS(pB3, lB + 6144);
    pA0 += 64; pA1 += 64; pA2 += 64; pA3 += 64;
    pB0 += 64; pB1 += 64; pB2 += 64; pB3 += 64;
    __syncthreads();

#pragma unroll
    for (int h = 0; h < 2; h++) {
      const short* fA = h ? fA1 : fA0;
      const short* fB = h ? fB1 : fB0;
      bf16x8 av[4], bw[4];
#pragma unroll
      for (int i = 0; i < 4; i++) av[i] = *(const bf16x8*)(fA + i * 1024);
#pragma unroll
      for (int j = 0; j < 4; j++) bw[j] = *(const bf16x8*)(fB + j * 1024);
#pragma unroll
      for (int i = 0; i < 4; i++)
#pragma unroll
        for (int j = 0; j < 4; j++)
          acc[i][j] = MFMA(av[i], bw[j], acc[i][j]);
    }
    __syncthreads();
  }

#pragma unroll
  for (int j = 0; j < 4; j++) {
    int col = bn + wn + j * 16 + l16;
    float bl = bias[col];
#pragma unroll
    for (int i = 0; i < 4; i++)
#pragma unroll
      for (int r = 0; r < 4; r++) {
        int row = bm + wm + i * 16 + quad * 4 + r;
        C[(size_t)row * 1024 + col] = acc[i][j][r] + bl;
      }
  }
}

extern "C" void kernel_launch(void* const* d_in, const int* in_sizes, int n_in,
                              void* d_out, int out_size, void* d_ws, size_t ws_size,
                              hipStream_t stream) {
  const float* emb = (const float*)d_in[0];
  const float* Wq  = (const float*)d_in[1];
  const float* bq  = (const float*)d_in[2];
  // d_in[3]=Wk, d_in[4]=bk, d_in[7]=w are mathematically dead (they cancel)
  const float* Wv  = (const float*)d_in[5];
  const float* bv  = (const float*)d_in[6];
  const float* Wo  = (const float*)d_in[8];
  const float* bo  = (const float*)d_in[9];
  float* out = (float*)d_out;

  // workspace layout (bytes)
  char* ws = (char*)d_ws;
  short* embB = (short*)(ws);                 // 8192*1024 bf16 = 16 MiB
  short* X    = (short*)(ws + 16777216);      // 8192*1024 bf16 = 16 MiB
  short* WqvT = (short*)(ws + 33554432);      // [WqT | WvT] 2048*1024 = 4 MiB
  short* WoT  = (short*)(ws + 37748736);      // 1024*1024 = 2 MiB
  // total: 39,845,888 bytes

  prep_kernel<<<768, 256, 0, stream>>>(emb, Wq, Wv, Wo, embB, WqvT, WoT);
  gemm_qv_kernel<<<dim3(64, 8), 256, 0, stream>>>(embB, WqvT, bq, bv, X);
  gemm_bt_kernel<<<dim3(64, 8), 256, 0, stream>>>(X, WoT, out, bo);
}

// Round 8
// 163.342 us; speedup vs baseline: 1.1665x; 1.1665x over previous
//
#include <hip/hip_runtime.h>

// Problem: B=64, S=128, D_MODEL=D_INNER=1024  ->  M = B*S = 8192, K = N = 1024.
// Reference simplifies: numerator/denominator == v exactly (dw>0, exp_k>0 cancel),
// so out = (sigmoid(emb@Wq+bq) * (emb@Wv+bv)) @ Wo + bo.  Wk, bk, w are dead inputs.
//
// R14: RESTORE the session-best configuration (R9, measured 162.2us):
//  - prep: grid 768, 64x64 f32->bf16 transpose tiles (BW-roofline, ~12us)
//  - qv:   R8 phased structure (measured 40.9us twice): BM=256 BN=128, 512thr,
//          2-slot dbuf 128KiB, 4 phases/K-tile, GLDS for tile j+2 spread over
//          ph2/ph3 (the one lever that ever moved qv), vmcnt(8) counted.
//  - bt:   simple 128x128 single-buffer, 256thr, 32KiB, grid (64,8) = 2 blk/CU
//          (905 TF; phased variants regress it).
// Session evidence (R7-R13): 8 structural variants; qv pinned at ~41us ≈ 840 TF
// for every schedule at this shape; R13's register-heavy port (VGPR 164, occ
// 10.6%) regressed to 68us. N=1024 caps full-occupancy tiles at 128 cols ->
// m97-structure class is the measured ceiling here. Controllable floor:
// kernels ~72us; harness fills 256MiB ~41us x2/rep (~82us) are fixed.

typedef short bf16x8 __attribute__((ext_vector_type(8)));  // 8 bf16 = 4 VGPRs
typedef float f32x4  __attribute__((ext_vector_type(4)));

__device__ __forceinline__ short f2bf(float f) {  // RNE fp32 -> bf16
  union { float f; unsigned u; } x; x.f = f;
  unsigned r = x.u + 0x7fffu + ((x.u >> 16) & 1u);
  return (short)(r >> 16);
}

struct alignas(16) S8 { short v[8]; };

#define GLDS(g, l) \
  __builtin_amdgcn_global_load_lds((const __attribute__((address_space(1))) void*)(g), \
                                   (__attribute__((address_space(3))) void*)(l), 16, 0, 0)
#define BAR()    __builtin_amdgcn_s_barrier()
#define PRIO(x)  __builtin_amdgcn_s_setprio(x)
#define SCHED0() __builtin_amdgcn_sched_barrier(0)
#define VMCNT(N) asm volatile("s_waitcnt vmcnt(" #N ")" ::: "memory")
#define LGKM0()  asm volatile("s_waitcnt lgkmcnt(0)" ::: "memory")
#define MFMA(a, b, c) __builtin_amdgcn_mfma_f32_16x16x32_bf16((a), (b), (c), 0, 0, 0)

// ---- Phase 0: emb fp32->bf16 + transpose/cast the three 1024x1024 weights ----
__global__ __launch_bounds__(256) void prep_kernel(
    const float* __restrict__ emb, const float* __restrict__ Wq, const float* __restrict__ Wv,
    const float* __restrict__ Wo, short* __restrict__ embB, short* __restrict__ WqvT,
    short* __restrict__ WoT) {
  __shared__ float tr[64 * 65];  // pad 65 breaks column-read conflicts
  const int t = threadIdx.x;
  const int bid = blockIdx.x;
  const int gdim = gridDim.x;

  // emb cast: 1048576 groups of 8 floats -> 8 bf16
  for (size_t i = (size_t)bid * 256 + t; i < 1048576; i += (size_t)gdim * 256) {
    const float4* p = (const float4*)emb + i * 2;
    float4 a = p[0], b = p[1];
    S8 s;
    s.v[0] = f2bf(a.x); s.v[1] = f2bf(a.y); s.v[2] = f2bf(a.z); s.v[3] = f2bf(a.w);
    s.v[4] = f2bf(b.x); s.v[5] = f2bf(b.y); s.v[6] = f2bf(b.z); s.v[7] = f2bf(b.w);
    ((S8*)embB)[i] = s;
  }

  // weight transposes: 3 * 256 = 768 tiles of 64x64 (one per block at grid 768)
  const int rr = t >> 4, cc4 = (t & 15) * 4;     // read coords
  const int orow = t >> 3, ocol8 = (t & 7) * 8;  // write coords
  for (int z = bid; z < 768; z += gdim) {
    const float* in; short* op; int ti;
    if (z < 256)      { in = Wq; op = WqvT;           ti = z; }
    else if (z < 512) { in = Wv; op = WqvT + 1048576; ti = z - 256; }
    else              { in = Wo; op = WoT;            ti = z - 512; }
    const int bx = (ti & 15) * 64, by = (ti >> 4) * 64;
    __syncthreads();  // protect LDS reuse across z-iterations
#pragma unroll
    for (int k = 0; k < 4; ++k) {
      float4 v = *(const float4*)&in[(size_t)(by + rr + 16 * k) * 1024 + bx + cc4];
      float* d = &tr[(rr + 16 * k) * 65 + cc4];
      d[0] = v.x; d[1] = v.y; d[2] = v.z; d[3] = v.w;
    }
    __syncthreads();
#pragma unroll
    for (int h = 0; h < 2; ++h) {
      const int oc = orow + 32 * h;  // output row within tile = input col
      S8 s;
#pragma unroll
      for (int i = 0; i < 8; ++i) s.v[i] = f2bf(tr[(ocol8 + i) * 65 + oc]);
      *(S8*)&op[(size_t)(bx + oc) * 1024 + by + ocol8] = s;  // 16B, 128B runs
    }
  }
}

// ---- Phase 1: X = sigmoid(embB@WqT+bq) * (embB@WvT+bv), bf16. ----
// R8 structure (measured 40.9us). BM=256 BN=128, 8 waves 4Mx2N, 2-slot dbuf
// 128 KiB, 4 phases/K-tile, GLDS spread over ph2/ph3, vmcnt(8). grid 256.
__global__ __launch_bounds__(512, 2) void gemm_qv_kernel(
    const short* __restrict__ A, const short* __restrict__ BT,  // BT=[WqT|WvT] 2048x1024
    const float* __restrict__ bq, const float* __restrict__ bv, short* __restrict__ X) {
  __shared__ short As[2][256 * 64];   // 64 KiB
  __shared__ short Bqs[2][128 * 64];  // 32 KiB
  __shared__ short Bvs[2][128 * 64];  // 32 KiB
  const int t = threadIdx.x;
  const int lane = t & 63;
  const int w = t >> 6;        // 0..7
  const int l16 = lane & 15;
  const int quad = lane >> 4;
  const int b = blockIdx.x;
  const int wg = (b & 7) * 32 + (b >> 3);  // bijective XCD swizzle (256%8==0)
  const int bm = (wg >> 3) * 256;
  const int bn = (wg & 7) * 128;
  const int wm = (w & 3) * 64;
  const int wn = (w >> 2) * 64;

  const int r8 = t >> 3;                        // 0..63: row within a 64-row chunk
  const int swe = ((t & 7) ^ (r8 & 7)) * 8;     // pre-swizzled global source chunk
  const short* gA = A + (size_t)(bm + r8) * 1024 + swe;
  const short* gq = BT + (size_t)(bn + r8) * 1024 + swe;
  const short* gv = BT + (size_t)(1024 + bn + r8) * 1024 + swe;
  short* lA = &As[0][0] + w * 512;   // wave-uniform base; HW adds lane*16B
  short* lq = &Bqs[0][0] + w * 512;
  short* lv = &Bvs[0][0] + w * 512;

  // full-tile stage (prologue only)
#define QV_STAGE(k, s) do {                                             \
    const short* a_ = gA + (k) * 64; short* la_ = lA + (s) * 16384;     \
    GLDS(a_, la_);               GLDS(a_ + 64 * 1024, la_ + 4096);      \
    GLDS(a_ + 128 * 1024, la_ + 8192); GLDS(a_ + 192 * 1024, la_ + 12288); \
    const short* q_ = gq + (k) * 64; short* lq_ = lq + (s) * 8192;      \
    GLDS(q_, lq_);               GLDS(q_ + 64 * 1024, lq_ + 4096);      \
    const short* v_ = gv + (k) * 64; short* lv_ = lv + (s) * 8192;      \
    GLDS(v_, lv_);               GLDS(v_ + 64 * 1024, lv_ + 4096);      \
  } while (0)

  const int csw0 = (quad ^ (l16 & 7)) * 8;        // k-chunk quad   (k-half 0)
  const int csw1 = ((quad + 4) ^ (l16 & 7)) * 8;  // k-chunk quad+4 (k-half 1)
  const short* fA0 = &As[0][0] + (wm + l16) * 64 + csw0;
  const short* fA1 = &As[0][0] + (wm + l16) * 64 + csw1;
  const short* fq0 = &Bqs[0][0] + (wn + l16) * 64 + csw0;
  const short* fq1 = &Bqs[0][0] + (wn + l16) * 64 + csw1;
  const short* fv0 = &Bvs[0][0] + (wn + l16) * 64 + csw0;
  const short* fv1 = &Bvs[0][0] + (wn + l16) * 64 + csw1;

  f32x4 aq[4][4] = {};
  f32x4 av[4][4] = {};

  QV_STAGE(0, 0);
  QV_STAGE(1, 1);

  for (int j = 0; j < 16; ++j) {
    const int s = j & 1;
    const short* sA0 = fA0 + s * 16384;
    const short* sA1 = fA1 + s * 16384;
    const short* sq0 = fq0 + s * 8192;
    const short* sq1 = fq1 + s * 8192;
    const short* sv0 = fv0 + s * 8192;
    const short* sv1 = fv1 + s * 8192;

    // tile j landed iff only tile j+1's 8 loads remain (in-order retirement)
    if (j < 15) { VMCNT(8); } else { VMCNT(0); }
    BAR();

    bf16x8 a0[4], a1[4], bq0[4], bq1[4], bv0[4], bv1[4];
    // ---- ph0: read A (both k-halves) + Bq k-half0 (12 reads); MFMA q k0 ----
#pragma unroll
    for (int i = 0; i < 4; ++i) {
      a0[i] = *(const bf16x8*)(sA0 + i * 1024);
      a1[i] = *(const bf16x8*)(sA1 + i * 1024);
      bq0[i] = *(const bf16x8*)(sq0 + i * 1024);
    }
    BAR(); LGKM0(); SCHED0(); PRIO(1);
#pragma unroll
    for (int i = 0; i < 4; ++i)
#pragma unroll
      for (int n = 0; n < 4; ++n)
        aq[i][n] = MFMA(a0[i], bq0[n], aq[i][n]);
    PRIO(0); BAR();
    // ---- ph1: read Bq k1 + Bv k0 + Bv k1 (12 reads); MFMA q k1 ----
#pragma unroll
    for (int i = 0; i < 4; ++i) {
      bq1[i] = *(const bf16x8*)(sq1 + i * 1024);
      bv0[i] = *(const bf16x8*)(sv0 + i * 1024);
      bv1[i] = *(const bf16x8*)(sv1 + i * 1024);
    }
    BAR(); LGKM0(); SCHED0(); PRIO(1);
#pragma unroll
    for (int i = 0; i < 4; ++i)
#pragma unroll
      for (int n = 0; n < 4; ++n)
        aq[i][n] = MFMA(a1[i], bq1[n], aq[i][n]);
    PRIO(0); BAR();
    // slot s fully consumed chip-wide -> staging tile j+2 into s is race-free.
    // ---- ph2: GLDS A of tile j+2 (4) interleaved with MFMA v k0 ----
    if (j < 14) {
      const short* a_ = gA + (j + 2) * 64; short* la_ = lA + s * 16384;
      GLDS(a_, la_);                     GLDS(a_ + 64 * 1024, la_ + 4096);
      GLDS(a_ + 128 * 1024, la_ + 8192); GLDS(a_ + 192 * 1024, la_ + 12288);
    }
    PRIO(1);
#pragma unroll
    for (int i = 0; i < 4; ++i)
#pragma unroll
      for (int n = 0; n < 4; ++n)
        av[i][n] = MFMA(a0[i], bv0[n], av[i][n]);
    PRIO(0); BAR();
    // ---- ph3: GLDS Bq,Bv of tile j+2 (4) interleaved with MFMA v k1 ----
    if (j < 14) {
      const short* q_ = gq + (j + 2) * 64; short* lq_ = lq + s * 8192;
      GLDS(q_, lq_); GLDS(q_ + 64 * 1024, lq_ + 4096);
      const short* v_ = gv + (j + 2) * 64; short* lv_ = lv + s * 8192;
      GLDS(v_, lv_); GLDS(v_ + 64 * 1024, lv_ + 4096);
    }
    PRIO(1);
#pragma unroll
    for (int i = 0; i < 4; ++i)
#pragma unroll
      for (int n = 0; n < 4; ++n)
        av[i][n] = MFMA(a1[i], bv1[n], av[i][n]);
    PRIO(0); BAR();
  }
#undef QV_STAGE

  // epilogue: C/D layout col=lane&15, row=(lane>>4)*4+reg  [m89/m91-verified]
#pragma unroll
  for (int n = 0; n < 4; ++n) {
    const int col = bn + wn + n * 16 + l16;
    const float bql = bq[col], bvl = bv[col];
#pragma unroll
    for (int i = 0; i < 4; ++i)
#pragma unroll
      for (int r = 0; r < 4; ++r) {
        const int row = bm + wm + i * 16 + quad * 4 + r;
        const float q = aq[i][n][r] + bql;
        const float v = av[i][n][r] + bvl;
        const float sg = 1.0f / (1.0f + __expf(-q));
        X[(size_t)row * 1024 + col] = f2bf(sg * v);
      }
  }
}

// ---- Phase 2: out = X @ WoT^T + bo, fp32. R9-proven structure: 128x128 tile,
// BK=64, 256 thr (4 waves 2x2, wave 64x64), 32 KiB LDS, grid (64,8) = 512
// blocks = 2 blocks/CU. Inter-block TLP hides the staging drain. ----
__global__ __launch_bounds__(256) void gemm_bt_kernel(
    const short* __restrict__ A, const short* __restrict__ BT, float* __restrict__ C,
    const float* __restrict__ bias) {
  __shared__ short As[128 * 64];  // 16 KiB
  __shared__ short Bs[128 * 64];  // 16 KiB
  const int t = threadIdx.x;
  const int lane = t & 63;
  const int w = t >> 6;
  const int l16 = lane & 15;
  const int quad = lane >> 4;
  const int bm = blockIdx.x * 128;
  const int bn = blockIdx.y * 128;
  const int wm = (w & 1) * 64;
  const int wn = (w >> 1) * 64;

  const int r8 = t >> 3;
  const int swe = ((t & 7) ^ (r8 & 7)) * 8;
  const short* pA0 = A + (size_t)(bm + r8) * 1024 + swe;
  const short* pA1 = pA0 + 32 * 1024;
  const short* pA2 = pA0 + 64 * 1024;
  const short* pA3 = pA0 + 96 * 1024;
  const short* pB0 = BT + (size_t)(bn + r8) * 1024 + swe;
  const short* pB1 = pB0 + 32 * 1024;
  const short* pB2 = pB0 + 64 * 1024;
  const short* pB3 = pB0 + 96 * 1024;
  short* lA = As + w * 512;
  short* lB = Bs + w * 512;

  const int qsw0 = (quad ^ (l16 & 7)) * 8;
  const int qsw1 = ((quad + 4) ^ (l16 & 7)) * 8;
  const short* fA0 = As + (wm + l16) * 64 + qsw0;
  const short* fA1 = As + (wm + l16) * 64 + qsw1;
  const short* fB0 = Bs + (wn + l16) * 64 + qsw0;
  const short* fB1 = Bs + (wn + l16) * 64 + qsw1;

  f32x4 acc[4][4] = {};

  for (int it = 0; it < 16; ++it) {
    GLDS(pA0, lA); GLDS(pA1, lA + 2048); GLDS(pA2, lA + 4096); GLDS(pA3, lA + 6144);
    GLDS(pB0, lB); GLDS(pB1, lB + 2048); GLDS(pB2, lB + 4096); GLDS(pB3, lB + 6144);
    pA0 += 64; pA1 += 64; pA2 += 64; pA3 += 64;
    pB0 += 64; pB1 += 64; pB2 += 64; pB3 += 64;
    __syncthreads();

#pragma unroll
    for (int h = 0; h < 2; h++) {
      const short* fA = h ? fA1 : fA0;
      const short* fB = h ? fB1 : fB0;
      bf16x8 av[4], bw[4];
#pragma unroll
      for (int i = 0; i < 4; i++) av[i] = *(const bf16x8*)(fA + i * 1024);
#pragma unroll
      for (int j = 0; j < 4; j++) bw[j] = *(const bf16x8*)(fB + j * 1024);
#pragma unroll
      for (int i = 0; i < 4; i++)
#pragma unroll
        for (int j = 0; j < 4; j++)
          acc[i][j] = MFMA(av[i], bw[j], acc[i][j]);
    }
    __syncthreads();
  }

#pragma unroll
  for (int j = 0; j < 4; j++) {
    int col = bn + wn + j * 16 + l16;
    float bl = bias[col];
#pragma unroll
    for (int i = 0; i < 4; i++)
#pragma unroll
      for (int r = 0; r < 4; r++) {
        int row = bm + wm + i * 16 + quad * 4 + r;
        C[(size_t)row * 1024 + col] = acc[i][j][r] + bl;
      }
  }
}

extern "C" void kernel_launch(void* const* d_in, const int* in_sizes, int n_in,
                              void* d_out, int out_size, void* d_ws, size_t ws_size,
                              hipStream_t stream) {
  const float* emb = (const float*)d_in[0];
  const float* Wq  = (const float*)d_in[1];
  const float* bq  = (const float*)d_in[2];
  // d_in[3]=Wk, d_in[4]=bk, d_in[7]=w are mathematically dead (they cancel)
  const float* Wv  = (const float*)d_in[5];
  const float* bv  = (const float*)d_in[6];
  const float* Wo  = (const float*)d_in[8];
  const float* bo  = (const float*)d_in[9];
  float* out = (float*)d_out;

  // workspace layout (bytes)
  char* ws = (char*)d_ws;
  short* embB = (short*)(ws);                 // 8192*1024 bf16 = 16 MiB
  short* X    = (short*)(ws + 16777216);      // 8192*1024 bf16 = 16 MiB
  short* WqvT = (short*)(ws + 33554432);      // [WqT | WvT] 2048*1024 = 4 MiB
  short* WoT  = (short*)(ws + 37748736);      // 1024*1024 = 2 MiB
  // total: 39,845,888 bytes

  prep_kernel<<<768, 256, 0, stream>>>(emb, Wq, Wv, Wo, embB, WqvT, WoT);
  gemm_qv_kernel<<<256, 512, 0, stream>>>(embB, WqvT, bq, bv, X);
  gemm_bt_kernel<<<dim3(64, 8), 256, 0, stream>>>(X, WoT, out, bo);
}